// Round 10
// baseline (552.096 us; speedup 1.0000x reference)
//
#include <hip/hip_runtime.h>
#include <math.h>

#define B_ 256
#define N_ 200
#define D_ 128
#define H_ 8
#define KD_ 16
#define L_ 3
#define FF_ 512
#define ROWS (B_*N_)          // 51200
#define BND (ROWS*D_)         // 6,553,600

typedef float f32x4 __attribute__((ext_vector_type(4)));
typedef _Float16 f16x4 __attribute__((ext_vector_type(4)));
typedef _Float16 f16x8 __attribute__((ext_vector_type(8)));

__device__ __forceinline__ ushort f2h_bits(float f) {
  _Float16 h = (_Float16)f;
  union { _Float16 h; ushort u; } v; v.h = h; return v.u;
}
__device__ __forceinline__ float h2f(ushort u) {
  union { ushort u; _Float16 h; } v; v.u = u; return (float)v.h;
}
// BN finalize from 128-float atomic accumulators (2 loads)
__device__ __forceinline__ void bn_reduce(const float* psum, const float* psq,
    const float* gamma, const float* beta, int c, float& sc, float& sh) {
  if (gamma == nullptr) { sc = 1.f; sh = 0.f; return; }
  float s = psum[c], q = psq[c];
  const float invM = 1.f / 51200.f;
  float m = s * invM;
  float v = fmaf(q, invM, -m * m);
  float rr = rsqrtf(v + 1e-5f);
  sc = rr * gamma[c];
  sh = fmaf(-m, sc, beta[c]);
}

// ---------------- init: embed (h fp16) + weight transposes + stat-zero, one launch ----------------
__global__ __launch_bounds__(256) void init_kernel(const float* __restrict__ x,
    const float* __restrict__ Wemb, const float* __restrict__ bemb,
    const float* __restrict__ Wo, const float* __restrict__ W2,
    ushort* __restrict__ h, ushort* __restrict__ woT, ushort* __restrict__ w2T,
    float* __restrict__ pa_s, float* __restrict__ pa_q,
    float* __restrict__ pb_s, float* __restrict__ pb_q)
{
  int blk = blockIdx.x, t = threadIdx.x;
  if (blk < 6400) {
    int i4 = blk * 256 + t;                 // ROWS*32 float4s
    int r  = i4 >> 5, c4 = i4 & 31;
    float x0 = x[2*r], x1 = x[2*r + 1];
    const float4 w0 = ((const float4*)Wemb)[c4];
    const float4 w1 = ((const float4*)Wemb)[32 + c4];
    const float4 bb = ((const float4*)bemb)[c4];
    ushort o16[4];
    o16[0] = f2h_bits(fmaf(x0, w0.x, fmaf(x1, w1.x, bb.x)));
    o16[1] = f2h_bits(fmaf(x0, w0.y, fmaf(x1, w1.y, bb.y)));
    o16[2] = f2h_bits(fmaf(x0, w0.z, fmaf(x1, w1.z, bb.z)));
    o16[3] = f2h_bits(fmaf(x0, w0.w, fmaf(x1, w1.w, bb.w)));
    uint2 p;
    p.x = (uint)o16[0] | ((uint)o16[1] << 16);
    p.y = (uint)o16[2] | ((uint)o16[3] << 16);
    ((uint2*)h)[i4] = p;
  } else if (blk < 7360) {
    int i = (blk - 6400) * 256 + t;         // 245760 exact
    if (i < 49152) {
      int l = i / 16384, r = i % 16384;
      int n = r >> 7, k = r & 127;
      int hh = k >> 4, kd = k & 15;
      woT[i] = f2h_bits(Wo[l*16384 + hh*2048 + kd*128 + n]);
    } else {
      int j = i - 49152;
      int l = j / 65536, r = j % 65536;
      int d = r >> 9, f = r & 511;
      w2T[j] = f2h_bits(W2[l*65536 + f*128 + d]);
    }
  } else {
    if (t < 128) { pa_s[t] = 0.f; pa_q[t] = 0.f; pb_s[t] = 0.f; pb_q[t] = 0.f; }
  }
}

// ------------- fold BN2(prev) into QKV weights; zero BN1 accumulators (block 1) -------------
__global__ __launch_bounds__(128) void fold_qkv(const float* __restrict__ Wq,
    const float* __restrict__ Wk, const float* __restrict__ Wv,
    const float* __restrict__ pb_s, const float* __restrict__ pb_q,
    const float* __restrict__ gamma, const float* __restrict__ beta,
    ushort* __restrict__ wh, float* __restrict__ bout,
    float* __restrict__ scout, float* __restrict__ shout,
    float* __restrict__ pa_s, float* __restrict__ pa_q)
{
  __shared__ float wsum[2];
  int n = blockIdx.x;                     // 0..383
  int k = threadIdx.x;                    // 0..127
  float sc, sh;
  bn_reduce(pb_s, pb_q, gamma, beta, k, sc, sh);
  if (n == 0) { scout[k] = sc; shout[k] = sh; }
  if (n == 1) { pa_s[k] = 0.f; pa_q[k] = 0.f; }   // zero BN1 accum before outproj
  int which = n >> 7, hh = (n >> 4) & 7, kd = n & 15;
  const float* src = (which == 0) ? Wq : (which == 1) ? Wk : Wv;
  float w = src[hh*2048 + k*16 + kd];
  if (which == 0) w *= 0.25f * 1.44269504088896340736f;   // fold 1/sqrt(KD)*log2(e) into Q
  wh[n*128 + k] = f2h_bits(w * sc);
  float p = sh * w;
#pragma unroll
  for (int d = 1; d < 64; d <<= 1) p += __shfl_xor(p, d);
  if ((k & 63) == 0) wsum[k >> 6] = p;
  __syncthreads();
  if (k == 0) bout[n] = wsum[0] + wsum[1];
}

// ------------- fold BN1 into W1 -------------
__global__ __launch_bounds__(128) void fold_w1(const float* __restrict__ W1,
    const float* __restrict__ b1,
    const float* __restrict__ pa_s, const float* __restrict__ pa_q,
    const float* __restrict__ gamma, const float* __restrict__ beta,
    ushort* __restrict__ wh, float* __restrict__ bout,
    float* __restrict__ scout, float* __restrict__ shout)
{
  __shared__ float wsum[2];
  int f = blockIdx.x;                     // 0..511
  int k = threadIdx.x;                    // 0..127
  float sc, sh;
  bn_reduce(pa_s, pa_q, gamma, beta, k, sc, sh);
  if (f == 0) { scout[k] = sc; shout[k] = sh; }
  float w = W1[k*512 + f];
  wh[f*128 + k] = f2h_bits(w * sc);
  float p = sh * w;
#pragma unroll
  for (int d = 1; d < 64; d <<= 1) p += __shfl_xor(p, d);
  if ((k & 63) == 0) wsum[k >> 6] = p;
  __syncthreads();
  if (k == 0) bout[f] = b1[f] + wsum[0] + wsum[1];
}

// ---------------- fp16 MFMA GEMM: A fp16, B fp16, 1 MFMA/acc ----------------
template<int K, bool BIAS, bool RELU, bool RESIDBN,
         bool OUTQKV, bool OUT16, bool STATS>
__global__ __launch_bounds__(256, 2) void gemm_mfma(
    const ushort* __restrict__ Ah,
    const ushort* __restrict__ Wh,
    const float* __restrict__ bias,
    const ushort* rh,
    const float* __restrict__ rsc, const float* __restrict__ rsh,
    ushort* o0, ushort* o1, ushort* o2,
    float* __restrict__ psum, float* __restrict__ psq, int Ntot)
{
  __shared__ ushort AhS[128*64];
  __shared__ ushort BhS[128*64];
  const int t    = threadIdx.x;
  // ---- XCD-bijective block swizzle ----
  const int nx   = gridDim.x;
  const int nwg  = nx * gridDim.y;
  const int lin  = blockIdx.y * nx + blockIdx.x;
  const int q8   = nwg >> 3, r8 = nwg & 7;
  const int xcd  = lin & 7, i8 = lin >> 3;
  const int wg   = (xcd < r8 ? xcd*(q8+1) : r8*(q8+1) + (xcd-r8)*q8) + i8;
  const int bm   = (wg / nx) * 128;
  const int bn   = (wg % nx) * 128;
  const int lane = t & 63;
  const int w    = t >> 6, wm = w >> 1, wn = w & 1;
  const int quad = lane >> 4, l15 = lane & 15;

  f32x4 acc[4][4];
#pragma unroll
  for (int i = 0; i < 4; i++)
#pragma unroll
    for (int j = 0; j < 4; j++) acc[i][j] = (f32x4){0.f, 0.f, 0.f, 0.f};

  const ushort* AhB = Ah + (size_t)bm * K;
  const ushort* BhB = Wh + (size_t)bn * K;

  for (int k0 = 0; k0 < K; k0 += 64) {
#pragma unroll
    for (int i = 0; i < 4; i++) {
      int idx = i * 256 + t;
      int row = idx >> 3, c = idx & 7;
      int k8  = c ^ (row & 7);
      size_t off = (size_t)row * K + k0 + k8 * 8;
      ((uint4*)AhS)[idx] = *(const uint4*)(AhB + off);
      ((uint4*)BhS)[idx] = *(const uint4*)(BhB + off);
    }
    __syncthreads();
#pragma unroll
    for (int ks = 0; ks < 2; ks++) {
      f16x8 ah[4], bh[4];
#pragma unroll
      for (int i = 0; i < 4; i++) {
        int row = wm * 64 + i * 16 + l15;
        int k8  = ks * 4 + quad;
        int ci  = k8 ^ (row & 7);
        ah[i] = ((const f16x8*)AhS)[row * 8 + ci];
        int nrow = wn * 64 + i * 16 + l15;
        int cj   = k8 ^ (nrow & 7);
        bh[i] = ((const f16x8*)BhS)[nrow * 8 + cj];
      }
#pragma unroll
      for (int i = 0; i < 4; i++)
#pragma unroll
        for (int j = 0; j < 4; j++)
          acc[i][j] = __builtin_amdgcn_mfma_f32_16x16x32_f16(ah[i], bh[j], acc[i][j], 0, 0, 0);
    }
    __syncthreads();
  }

  float bv[4], scv[4], shv[4];
#pragma unroll
  for (int j = 0; j < 4; j++) {
    int col = bn + wn*64 + j*16 + l15;
    if (BIAS)    bv[j]  = bias[col];
    if (RESIDBN) { scv[j] = rsc[col]; shv[j] = rsh[col]; }
  }
  float sj[4] = {0.f,0.f,0.f,0.f}, qj[4] = {0.f,0.f,0.f,0.f};
#pragma unroll
  for (int i = 0; i < 4; i++) {
#pragma unroll
    for (int r = 0; r < 4; r++) {
      int row = bm + wm*64 + i*16 + quad*4 + r;
#pragma unroll
      for (int j = 0; j < 4; j++) {
        int col = bn + wn*64 + j*16 + l15;
        float v = acc[i][j][r];
        if (BIAS)    v += bv[j];
        if (RELU)    v = fmaxf(v, 0.f);
        if (RESIDBN) {
          float rr = h2f(rh[(size_t)row * Ntot + col]);
          v += fmaf(rr, scv[j], shv[j]);
        }
        if (OUTQKV) {
          if (bn == 0) {                     // Q (pre-scaled) -> head-major fp16
            o0[((size_t)(col >> 4) * ROWS + row) * 16 + (col & 15)] = f2h_bits(v);
          } else if (bn == 128) {            // K -> head-major fp16
            int c = col - 128;
            o1[((size_t)(c >> 4) * ROWS + row) * 16 + (c & 15)] = f2h_bits(v);
          } else {                           // V -> head-major single fp16
            int c = col - 256;
            o2[((size_t)(c >> 4) * ROWS + row) * 16 + (c & 15)] = f2h_bits(v);
          }
        }
        if (OUT16) o0[(size_t)row * Ntot + col] = f2h_bits(v);
        if (STATS) { sj[j] += v; qj[j] = fmaf(v, v, qj[j]); }
      }
    }
  }
  if (STATS) {
#pragma unroll
    for (int j = 0; j < 4; j++) {
      sj[j] += __shfl_xor(sj[j], 16); sj[j] += __shfl_xor(sj[j], 32);
      qj[j] += __shfl_xor(qj[j], 16); qj[j] += __shfl_xor(qj[j], 32);
    }
    float* ssum = (float*)AhS;     // safe: k-loop ended with barrier
    float* ssq  = ssum + 128;
    if (t < 128) { ssum[t] = 0.f; ssq[t] = 0.f; }
    __syncthreads();
    if (quad == 0) {
#pragma unroll
      for (int j = 0; j < 4; j++) {
        int col = wn*64 + j*16 + l15;
        atomicAdd(&ssum[col], sj[j]);
        atomicAdd(&ssq[col],  qj[j]);
      }
    }
    __syncthreads();
    if (t < 128) {
      atomicAdd(&psum[t], ssum[t]);
      atomicAdd(&psq[t],  ssq[t]);
    }
  }
}

// ---------------- fused FFN: out = ReLU(h@W1 + b1f)@W2 + b2 + BN1-resid; hid stays in LDS ----------------
// Block = 128 rows. A (h panel) resident in LDS; 4 f-chunks of 128:
// stage W1c -> MFMA hid -> relu->fp16 -> HB -> stage W2c (same buffer) -> MFMA out-accum.
// Accumulation order identical to separate FFN1/FFN2 kernels (bitwise same result).
__global__ __launch_bounds__(256, 1) void ffn_fused(
    const ushort* __restrict__ h,        // [ROWS][128] fp16 (A; also residual source)
    const ushort* __restrict__ w1,       // [512][128] folded fp16
    const float* __restrict__ b1f,       // [512] folded bias
    const ushort* __restrict__ w2t,      // [128][512] fp16
    const float* __restrict__ b2,        // [128]
    const float* __restrict__ rsc, const float* __restrict__ rsh,
    ushort* hout,                        // aliases h (in-place row update)
    float* __restrict__ psum, float* __restrict__ psq)
{
  __shared__ ushort Ash[2*128*64];       // 32KB  A, halves by k
  __shared__ ushort WB [2*128*64];       // 32KB  W1 chunk, then W2 chunk
  __shared__ ushort HB [2*128*72];       // 36KB  relu(hid) chunk, pitch 72 (bank stagger)
  const int t    = threadIdx.x;
  const int bm   = blockIdx.x * 128;
  const int lane = t & 63;
  const int w    = t >> 6, wm = w >> 1, wn = w & 1;
  const int quad = lane >> 4, l15 = lane & 15;

  // ---- stage A (128 rows x 128 k) ----
  {
    const ushort* AB = h + (size_t)bm * 128;
    for (int half = 0; half < 2; half++)
#pragma unroll
      for (int i = 0; i < 4; i++) {
        int idx = i * 256 + t;
        int row = idx >> 3, c = idx & 7;
        int k8  = c ^ (row & 7);
        ((uint4*)(Ash + half*8192))[idx] = *(const uint4*)(AB + (size_t)row*128 + half*64 + k8*8);
      }
  }

  f32x4 aco[4][4];
#pragma unroll
  for (int i = 0; i < 4; i++)
#pragma unroll
    for (int j = 0; j < 4; j++) aco[i][j] = (f32x4){0.f, 0.f, 0.f, 0.f};

  __syncthreads();

  for (int ch = 0; ch < 4; ch++) {
    // ---- stage W1 chunk: rows f0+0..127, k 0..127 ----
    {
      const ushort* W1B = w1 + (size_t)ch * 128 * 128;
      for (int half = 0; half < 2; half++)
#pragma unroll
        for (int i = 0; i < 4; i++) {
          int idx = i * 256 + t;
          int row = idx >> 3, c = idx & 7;
          int k8  = c ^ (row & 7);
          ((uint4*)(WB + half*8192))[idx] = *(const uint4*)(W1B + (size_t)row*128 + half*64 + k8*8);
        }
    }
    __syncthreads();
    // ---- hid chunk MFMA: [row][f] 128x128, K=128 ----
    f32x4 ach[4][4];
#pragma unroll
    for (int i = 0; i < 4; i++)
#pragma unroll
      for (int j = 0; j < 4; j++) ach[i][j] = (f32x4){0.f, 0.f, 0.f, 0.f};
#pragma unroll
    for (int ks = 0; ks < 4; ks++) {
      int half = ks >> 1, k8 = (ks & 1)*4 + quad;
      f16x8 ah[4], bh[4];
#pragma unroll
      for (int i = 0; i < 4; i++) {
        int row = wm*64 + i*16 + l15;
        int ci  = k8 ^ (row & 7);
        ah[i] = ((const f16x8*)(Ash + half*8192))[row*8 + ci];
        int fr = wn*64 + i*16 + l15;
        int cj  = k8 ^ (fr & 7);
        bh[i] = ((const f16x8*)(WB + half*8192))[fr*8 + cj];
      }
#pragma unroll
      for (int i = 0; i < 4; i++)
#pragma unroll
        for (int j = 0; j < 4; j++)
          ach[i][j] = __builtin_amdgcn_mfma_f32_16x16x32_f16(ah[i], bh[j], ach[i][j], 0, 0, 0);
    }
    __syncthreads();       // all waves done reading WB (W1c)
    // ---- bias + relu -> HB (fp16, swizzled, pitch 72) ----
    {
      float bv1[4];
#pragma unroll
      for (int j = 0; j < 4; j++) bv1[j] = b1f[ch*128 + wn*64 + j*16 + l15];
#pragma unroll
      for (int i = 0; i < 4; i++)
#pragma unroll
        for (int r = 0; r < 4; r++) {
          int row = wm*64 + i*16 + quad*4 + r;
#pragma unroll
          for (int j = 0; j < 4; j++) {
            float hv = fmaxf(ach[i][j][r] + bv1[j], 0.f);
            int k6  = j*16 + l15;
            int ci8 = (k6 >> 3) ^ (row & 7);
            HB[(wn*128 + row)*72 + ci8*8 + (l15 & 7)] = f2h_bits(hv);
          }
        }
    }
    // ---- stage W2 chunk: rows d 0..127, k = f0..f0+127 (pitch 512) ----
    {
      const ushort* W2B = w2t + ch * 128;
      for (int half = 0; half < 2; half++)
#pragma unroll
        for (int i = 0; i < 4; i++) {
          int idx = i * 256 + t;
          int row = idx >> 3, c = idx & 7;
          int k8  = c ^ (row & 7);
          ((uint4*)(WB + half*8192))[idx] = *(const uint4*)(W2B + (size_t)row*512 + half*64 + k8*8);
        }
    }
    __syncthreads();       // HB + WB(W2c) ready
    // ---- out accumulate: [row][d] 128x128, K=f 128 ----
#pragma unroll
    for (int ks = 0; ks < 4; ks++) {
      int half = ks >> 1, k8 = (ks & 1)*4 + quad;
      f16x8 ah[4], bh[4];
#pragma unroll
      for (int i = 0; i < 4; i++) {
        int row = wm*64 + i*16 + l15;
        int ci  = k8 ^ (row & 7);
        ah[i] = *(const f16x8*)&HB[(half*128 + row)*72 + ci*8];
        int dr = wn*64 + i*16 + l15;
        int cj  = k8 ^ (dr & 7);
        bh[i] = ((const f16x8*)(WB + half*8192))[dr*8 + cj];
      }
#pragma unroll
      for (int i = 0; i < 4; i++)
#pragma unroll
        for (int j = 0; j < 4; j++)
          aco[i][j] = __builtin_amdgcn_mfma_f32_16x16x32_f16(ah[i], bh[j], aco[i][j], 0, 0, 0);
    }
    __syncthreads();       // done reading HB + WB; next chunk may overwrite
  }

  // ---- epilogue: + b2 + BN1-folded residual (residual read from Ash!) -> h + BN2 stats ----
  float bv[4], scv[4], shv[4];
#pragma unroll
  for (int j = 0; j < 4; j++) {
    int col = wn*64 + j*16 + l15;
    bv[j]  = b2[col];
    scv[j] = rsc[col]; shv[j] = rsh[col];
  }
  float sj[4] = {0.f,0.f,0.f,0.f}, qj[4] = {0.f,0.f,0.f,0.f};
#pragma unroll
  for (int i = 0; i < 4; i++) {
#pragma unroll
    for (int r = 0; r < 4; r++) {
      int rloc = wm*64 + i*16 + quad*4 + r;
      int row  = bm + rloc;
#pragma unroll
      for (int j = 0; j < 4; j++) {
        int col = wn*64 + j*16 + l15;
        float v = aco[i][j][r] + bv[j];
        // residual = h[row][col] = A[rloc][k=col], still resident in Ash
        int k6 = col & 63, half = col >> 6;
        int ci = (k6 >> 3) ^ (rloc & 7);
        float rr = h2f(Ash[half*8192 + rloc*64 + ci*8 + (k6 & 7)]);
        v += fmaf(rr, scv[j], shv[j]);
        hout[(size_t)row * 128 + col] = f2h_bits(v);
        sj[j] += v; qj[j] = fmaf(v, v, qj[j]);
      }
    }
  }
#pragma unroll
  for (int j = 0; j < 4; j++) {
    sj[j] += __shfl_xor(sj[j], 16); sj[j] += __shfl_xor(sj[j], 32);
    qj[j] += __shfl_xor(qj[j], 16); qj[j] += __shfl_xor(qj[j], 32);
  }
  __syncthreads();               // all residual reads from Ash complete
  float* ssum = (float*)Ash;
  float* ssq  = ssum + 128;
  if (t < 128) { ssum[t] = 0.f; ssq[t] = 0.f; }
  __syncthreads();
  if (quad == 0) {
#pragma unroll
    for (int j = 0; j < 4; j++) {
      int col = wn*64 + j*16 + l15;
      atomicAdd(&ssum[col], sj[j]);
      atomicAdd(&ssq[col],  qj[j]);
    }
  }
  __syncthreads();
  if (t < 128) {
    atomicAdd(&psum[t], ssum[t]);
    atomicAdd(&psq[t],  ssq[t]);
  }
}

// ---------------- MFMA fused attention; block 0 zeroes BN2 accumulators ----------------
__global__ __launch_bounds__(256) void attn_kernel(const ushort* __restrict__ qs,
    const ushort* __restrict__ ks, const ushort* __restrict__ vh,
    ushort* __restrict__ hd, float* __restrict__ pb_s, float* __restrict__ pb_q)
{
  __shared__ __align__(16) _Float16 Ksh[208*24];    // [key][kd], pitch 24
  __shared__ __align__(16) _Float16 VTh[16*216];    // V^T [kd][key], pitch 216
  const int b  = blockIdx.x >> 3;
  const int hh = blockIdx.x & 7;
  const int t  = threadIdx.x;
  if (blockIdx.x == 0 && t < 128) { pb_s[t] = 0.f; pb_q[t] = 0.f; }  // zero BN2 accum
  const size_t rb = (size_t)b * N_;
  const size_t hb = ((size_t)hh * ROWS + rb) * 16;   // element base of this (head, batch)

  // ---- stage K [208][24]: 16B loads, zero pad rows 200..207 ----
  for (int i = t; i < 208*2; i += 256) {
    int n = i >> 1, half = i & 1;
    uint4 kv = {0u, 0u, 0u, 0u};
    if (n < N_) kv = *(const uint4*)(ks + hb + n*16 + half*8);
    *(uint4*)&Ksh[n*24 + half*8] = kv;
  }
  // ---- stage V^T: 16B loads + LDS transpose scatter ----
  for (int i = t; i < 208*2; i += 256) {
    int n = i >> 1, half = i & 1;
    uint4 v0 = {0u, 0u, 0u, 0u};
    if (n < N_) v0 = *(const uint4*)(vh + hb + n*16 + half*8);
    const ushort* e0 = (const ushort*)&v0;
#pragma unroll
    for (int q = 0; q < 8; q++)
      ((ushort*)VTh)[(half*8 + q)*216 + n] = e0[q];
  }
  __syncthreads();

  const int lane = t & 63;
  const int w    = t >> 6;
  const int l15  = lane & 15;
  const int g    = lane >> 4;

  for (int qt = w; qt < 13; qt += 4) {
    int qr  = qt*16 + l15;                 // query row in [0,208)
    int qrc = qr < N_ ? qr : N_-1;         // clamp pad rows (results discarded)
    f16x4 bq = *(const f16x4*)(qs + hb + (size_t)qrc*16 + g*4);

    // S^T tiles: ct[kt] holds scores (log2-units) for keys kt*16+g*4+r, query q=l15
    f32x4 ct[13];
#pragma unroll
    for (int kt = 0; kt < 13; kt++) {
      f16x4 ak = *(const f16x4*)&Ksh[(kt*16 + l15)*24 + g*4];
      ct[kt] = __builtin_amdgcn_mfma_f32_16x16x16f16(ak, bq, (f32x4){0.f,0.f,0.f,0.f}, 0, 0, 0);
    }
    // mask pad keys (192+g*4+r >= 200)
#pragma unroll
    for (int r = 0; r < 4; r++)
      if (g*4 + r >= 8) ct[12][r] = -1e30f;

    // row max over 13 tiles then across lane groups
    float m0 = -1e30f, m1 = -1e30f;
#pragma unroll
    for (int kt = 0; kt < 13; kt++) {
      m0 = fmaxf(m0, fmaxf(ct[kt][0], ct[kt][1]));
      m1 = fmaxf(m1, fmaxf(ct[kt][2], ct[kt][3]));
    }
    float m = fmaxf(m0, m1);
    m = fmaxf(m, __shfl_xor(m, 16));
    m = fmaxf(m, __shfl_xor(m, 32));

    // exp2 + row sum
    float la0 = 0.f, la1 = 0.f, la2 = 0.f, la3 = 0.f;
#pragma unroll
    for (int kt = 0; kt < 13; kt++) {
      float p0 = __builtin_amdgcn_exp2f(ct[kt][0] - m);
      float p1 = __builtin_amdgcn_exp2f(ct[kt][1] - m);
      float p2 = __builtin_amdgcn_exp2f(ct[kt][2] - m);
      float p3 = __builtin_amdgcn_exp2f(ct[kt][3] - m);
      la0 += p0; la1 += p1; la2 += p2; la3 += p3;
      ct[kt][0] = p0; ct[kt][1] = p1; ct[kt][2] = p2; ct[kt][3] = p3;
    }
    float l = (la0 + la1) + (la2 + la3);
    l += __shfl_xor(l, 16);
    l += __shfl_xor(l, 32);

    // O^T = V^T P^T — P^T B-frags come straight from ct
    f32x4 och = {0.f,0.f,0.f,0.f};
#pragma unroll
    for (int kt = 0; kt < 13; kt++) {
      f16x4 pt = { (_Float16)ct[kt][0], (_Float16)ct[kt][1],
                   (_Float16)ct[kt][2], (_Float16)ct[kt][3] };
      f16x4 avh = *(const f16x4*)&VTh[l15*216 + kt*16 + g*4];
      och = __builtin_amdgcn_mfma_f32_16x16x16f16(avh, pt, och, 0, 0, 0);
    }

    if (qr < N_) {
      float inv = __builtin_amdgcn_rcpf(l);
      ushort o16[4];
#pragma unroll
      for (int r = 0; r < 4; r++) o16[r] = f2h_bits(och[r] * inv);
      uint2 p;
      p.x = (uint)o16[0] | ((uint)o16[1] << 16);
      p.y = (uint)o16[2] | ((uint)o16[3] << 16);
      *(uint2*)(hd + (rb + qr)*128 + hh*16 + g*4) = p;
    }
  }
}

// ---------------- final: BN2-finalize + apply + per-batch mean ----------------
__global__ __launch_bounds__(256) void bn_mean_final(const ushort* __restrict__ h,
    const float* __restrict__ pb_s, const float* __restrict__ pb_q,
    const float* __restrict__ gamma, const float* __restrict__ beta,
    float* __restrict__ outh, float* __restrict__ mout)
{
  __shared__ float part[2][128];
  int b = blockIdx.x;
  int t = threadIdx.x;
  int d = t & 127, half = t >> 7;
  float sc, sh;
  bn_reduce(pb_s, pb_q, gamma, beta, d, sc, sh);
  float s = 0.f;
  for (int n = half*100; n < half*100 + 100; n++) {
    size_t idx = ((size_t)b * N_ + n) * 128 + d;
    float v = fmaf(h2f(h[idx]), sc, sh);
    outh[idx] = v;
    s += v;
  }
  part[half][d] = s;
  __syncthreads();
  if (half == 0) mout[b * 128 + d] = (part[0][d] + part[1][d]) * (1.f / N_);
}

extern "C" void kernel_launch(void* const* d_in, const int* in_sizes, int n_in,
                              void* d_out, int out_size, void* d_ws, size_t ws_size,
                              hipStream_t stream)
{
  const float* x    = (const float*)d_in[0];
  const float* Wemb = (const float*)d_in[1];
  const float* bemb = (const float*)d_in[2];
  const float* Wq   = (const float*)d_in[3];
  const float* Wk   = (const float*)d_in[4];
  const float* Wv   = (const float*)d_in[5];
  const float* Wo   = (const float*)d_in[6];
  const float* bn1g = (const float*)d_in[7];
  const float* bn1b = (const float*)d_in[8];
  const float* W1   = (const float*)d_in[9];
  const float* b1   = (const float*)d_in[10];
  const float* W2   = (const float*)d_in[11];
  const float* b2   = (const float*)d_in[12];
  const float* bn2g = (const float*)d_in[13];
  const float* bn2b = (const float*)d_in[14];
  float* out = (float*)d_out;

  char* wsb = (char*)d_ws;
  ushort* h     = (ushort*)wsb;                     // 13,107,200 B (fp16 residual stream)
  char*   phase = wsb + 13107200;                   // attn scratch
  ushort* qsb   = (ushort*)phase;                   // 13,107,200 B (Q head-major)
  ushort* ksb   = (ushort*)(phase + 13107200);      // 13,107,200 B (K head-major)
  ushort* vhh   = (ushort*)(phase + 26214400);      // 13,107,200 B (V fp16)
  ushort* hd    = (ushort*)(phase + 39321600);      // 13,107,200 B (heads fp16)
  char*   wp    = wsb + 65536000;
  ushort* woT   = (ushort*)wp;                      // 98,304 B
  ushort* w2T   = (ushort*)(wp + 98304);            // 393,216 B
  ushort* fqkvw = (ushort*)(wp + 491520);           // 98,304 B
  ushort* fw1w  = (ushort*)(wp + 589824);           // 131,072 B
  float*  fqkv_b = (float*)(wp + 720896);           // 1,536 B
  float*  fw1_b  = (float*)(wp + 722432);           // 2,048 B
  float*  pa_s   = (float*)(wp + 724480);           // 512 B (BN1 sum accum)
  float*  pa_q   = (float*)(wp + 724992);           // 512 B
  float*  pb_s   = (float*)(wp + 725504);           // 512 B (BN2 sum accum)
  float*  pb_q   = (float*)(wp + 726016);           // 512 B
  float*  sc_a   = (float*)(wp + 726528);
  float*  sh_a   = (float*)(wp + 727040);
  float*  sc_b   = (float*)(wp + 727552);
  float*  sh_b   = (float*)(wp + 728064);

  init_kernel<<<7361, 256, 0, stream>>>(x, Wemb, bemb, Wo, W2, h, woT, w2T,
                                        pa_s, pa_q, pb_s, pb_q);

  for (int l = 0; l < L_; l++) {
    // fold BN2(prev layer) into QKV weights; publishes sc_b/sh_b; zeroes BN1 accum
    fold_qkv<<<384, 128, 0, stream>>>(Wq + l*16384, Wk + l*16384, Wv + l*16384,
                                      pb_s, pb_q,
                                      l == 0 ? nullptr : bn2g + (l-1)*128,
                                      l == 0 ? nullptr : bn2b + (l-1)*128,
                                      fqkvw, fqkv_b, sc_b, sh_b, pa_s, pa_q);
    // QKV projection -> head-major Q/K/V fp16
    gemm_mfma<128, true, false, false, true, false, false>
        <<<dim3(3, 400), 256, 0, stream>>>(
        h, fqkvw, fqkv_b, nullptr, nullptr, nullptr,
        qsb, ksb, vhh, nullptr, nullptr, 384);
    // attention -> heads fp16 [row][128]; zeroes BN2 accumulators
    attn_kernel<<<B_ * H_, 256, 0, stream>>>(qsb, ksb, vhh, hd, pb_s, pb_q);
    // out-proj + BN-folded residual -> h fp16 + BN1 stats (atomic)
    gemm_mfma<128, false, false, true, false, true, true>
        <<<dim3(1, 400), 256, 0, stream>>>(
        hd, woT + l*16384, nullptr, h, sc_b, sh_b,
        h, nullptr, nullptr, pa_s, pa_q, 128);
    // fold BN1 into W1; publishes sc_a/sh_a
    fold_w1<<<512, 128, 0, stream>>>(W1 + l*65536, b1 + l*512,
                                     pa_s, pa_q, bn1g + l*128, bn1b + l*128,
                                     fw1w, fw1_b, sc_a, sh_a);
    // fused FFN1+ReLU+FFN2 + bias + BN1-folded residual -> h fp16 + BN2 stats (atomic)
    ffn_fused<<<400, 256, 0, stream>>>(
        h, fw1w, fw1_b, w2T + l*65536, b2 + l*128, sc_a, sh_a,
        h, pb_s, pb_q);
  }

  bn_mean_final<<<B_, 256, 0, stream>>>(h, pb_s, pb_q,
                                        bn2g + 2*128, bn2b + 2*128, out, out + BND);
}

// Round 11
// 496.138 us; speedup vs baseline: 1.1128x; 1.1128x over previous
//
#include <hip/hip_runtime.h>
#include <math.h>

#define B_ 256
#define N_ 200
#define D_ 128
#define H_ 8
#define KD_ 16
#define L_ 3
#define FF_ 512
#define ROWS (B_*N_)          // 51200
#define BND (ROWS*D_)         // 6,553,600

typedef float f32x4 __attribute__((ext_vector_type(4)));
typedef _Float16 f16x4 __attribute__((ext_vector_type(4)));
typedef _Float16 f16x8 __attribute__((ext_vector_type(8)));

__device__ __forceinline__ ushort f2h_bits(float f) {
  _Float16 h = (_Float16)f;
  union { _Float16 h; ushort u; } v; v.h = h; return v.u;
}
__device__ __forceinline__ float h2f(ushort u) {
  union { ushort u; _Float16 h; } v; v.u = u; return (float)v.h;
}
// BN finalize from 128-float atomic accumulators (2 loads)
__device__ __forceinline__ void bn_reduce(const float* psum, const float* psq,
    const float* gamma, const float* beta, int c, float& sc, float& sh) {
  if (gamma == nullptr) { sc = 1.f; sh = 0.f; return; }
  float s = psum[c], q = psq[c];
  const float invM = 1.f / 51200.f;
  float m = s * invM;
  float v = fmaf(q, invM, -m * m);
  float rr = rsqrtf(v + 1e-5f);
  sc = rr * gamma[c];
  sh = fmaf(-m, sc, beta[c]);
}

// ---------------- init: embed (h fp16) + weight transposes + stat-zero, one launch ----------------
__global__ __launch_bounds__(256) void init_kernel(const float* __restrict__ x,
    const float* __restrict__ Wemb, const float* __restrict__ bemb,
    const float* __restrict__ Wo, const float* __restrict__ W2,
    ushort* __restrict__ h, ushort* __restrict__ woT, ushort* __restrict__ w2T,
    float* __restrict__ pa_s, float* __restrict__ pa_q,
    float* __restrict__ pb_s, float* __restrict__ pb_q)
{
  int blk = blockIdx.x, t = threadIdx.x;
  if (blk < 6400) {
    int i4 = blk * 256 + t;                 // ROWS*32 float4s
    int r  = i4 >> 5, c4 = i4 & 31;
    float x0 = x[2*r], x1 = x[2*r + 1];
    const float4 w0 = ((const float4*)Wemb)[c4];
    const float4 w1 = ((const float4*)Wemb)[32 + c4];
    const float4 bb = ((const float4*)bemb)[c4];
    ushort o16[4];
    o16[0] = f2h_bits(fmaf(x0, w0.x, fmaf(x1, w1.x, bb.x)));
    o16[1] = f2h_bits(fmaf(x0, w0.y, fmaf(x1, w1.y, bb.y)));
    o16[2] = f2h_bits(fmaf(x0, w0.z, fmaf(x1, w1.z, bb.z)));
    o16[3] = f2h_bits(fmaf(x0, w0.w, fmaf(x1, w1.w, bb.w)));
    uint2 p;
    p.x = (uint)o16[0] | ((uint)o16[1] << 16);
    p.y = (uint)o16[2] | ((uint)o16[3] << 16);
    ((uint2*)h)[i4] = p;
  } else if (blk < 7360) {
    int i = (blk - 6400) * 256 + t;         // 245760 exact
    if (i < 49152) {
      int l = i / 16384, r = i % 16384;
      int n = r >> 7, k = r & 127;
      int hh = k >> 4, kd = k & 15;
      woT[i] = f2h_bits(Wo[l*16384 + hh*2048 + kd*128 + n]);
    } else {
      int j = i - 49152;
      int l = j / 65536, r = j % 65536;
      int d = r >> 9, f = r & 511;
      w2T[j] = f2h_bits(W2[l*65536 + f*128 + d]);
    }
  } else {
    if (t < 128) { pa_s[t] = 0.f; pa_q[t] = 0.f; pb_s[t] = 0.f; pb_q[t] = 0.f; }
  }
}

// ------------- fold BN2(prev) into QKV weights; zero BN1 accumulators (block 1) -------------
__global__ __launch_bounds__(128) void fold_qkv(const float* __restrict__ Wq,
    const float* __restrict__ Wk, const float* __restrict__ Wv,
    const float* __restrict__ pb_s, const float* __restrict__ pb_q,
    const float* __restrict__ gamma, const float* __restrict__ beta,
    ushort* __restrict__ wh, float* __restrict__ bout,
    float* __restrict__ scout, float* __restrict__ shout,
    float* __restrict__ pa_s, float* __restrict__ pa_q)
{
  __shared__ float wsum[2];
  int n = blockIdx.x;                     // 0..383
  int k = threadIdx.x;                    // 0..127
  float sc, sh;
  bn_reduce(pb_s, pb_q, gamma, beta, k, sc, sh);
  if (n == 0) { scout[k] = sc; shout[k] = sh; }
  if (n == 1) { pa_s[k] = 0.f; pa_q[k] = 0.f; }   // zero BN1 accum before outproj
  int which = n >> 7, hh = (n >> 4) & 7, kd = n & 15;
  const float* src = (which == 0) ? Wq : (which == 1) ? Wk : Wv;
  float w = src[hh*2048 + k*16 + kd];
  if (which == 0) w *= 0.25f * 1.44269504088896340736f;   // fold 1/sqrt(KD)*log2(e) into Q
  wh[n*128 + k] = f2h_bits(w * sc);
  float p = sh * w;
#pragma unroll
  for (int d = 1; d < 64; d <<= 1) p += __shfl_xor(p, d);
  if ((k & 63) == 0) wsum[k >> 6] = p;
  __syncthreads();
  if (k == 0) bout[n] = wsum[0] + wsum[1];
}

// ------------- fold BN1 into W1 -------------
__global__ __launch_bounds__(128) void fold_w1(const float* __restrict__ W1,
    const float* __restrict__ b1,
    const float* __restrict__ pa_s, const float* __restrict__ pa_q,
    const float* __restrict__ gamma, const float* __restrict__ beta,
    ushort* __restrict__ wh, float* __restrict__ bout,
    float* __restrict__ scout, float* __restrict__ shout)
{
  __shared__ float wsum[2];
  int f = blockIdx.x;                     // 0..511
  int k = threadIdx.x;                    // 0..127
  float sc, sh;
  bn_reduce(pa_s, pa_q, gamma, beta, k, sc, sh);
  if (f == 0) { scout[k] = sc; shout[k] = sh; }
  float w = W1[k*512 + f];
  wh[f*128 + k] = f2h_bits(w * sc);
  float p = sh * w;
#pragma unroll
  for (int d = 1; d < 64; d <<= 1) p += __shfl_xor(p, d);
  if ((k & 63) == 0) wsum[k >> 6] = p;
  __syncthreads();
  if (k == 0) bout[f] = b1[f] + wsum[0] + wsum[1];
}

// ---------------- fp16 MFMA GEMM: A fp16, B fp16, 1 MFMA/acc ----------------
template<int K, bool BIAS, bool RELU, bool RESIDBN,
         bool OUTQKV, bool OUT16, bool STATS>
__global__ __launch_bounds__(256, 2) void gemm_mfma(
    const ushort* __restrict__ Ah,
    const ushort* __restrict__ Wh,
    const float* __restrict__ bias,
    const ushort* rh,
    const float* __restrict__ rsc, const float* __restrict__ rsh,
    ushort* o0, ushort* o1, ushort* o2,
    float* __restrict__ psum, float* __restrict__ psq, int Ntot)
{
  __shared__ ushort AhS[128*64];
  __shared__ ushort BhS[128*64];
  const int t    = threadIdx.x;
  // ---- XCD-bijective block swizzle ----
  const int nx   = gridDim.x;
  const int nwg  = nx * gridDim.y;
  const int lin  = blockIdx.y * nx + blockIdx.x;
  const int q8   = nwg >> 3, r8 = nwg & 7;
  const int xcd  = lin & 7, i8 = lin >> 3;
  const int wg   = (xcd < r8 ? xcd*(q8+1) : r8*(q8+1) + (xcd-r8)*q8) + i8;
  const int bm   = (wg / nx) * 128;
  const int bn   = (wg % nx) * 128;
  const int lane = t & 63;
  const int w    = t >> 6, wm = w >> 1, wn = w & 1;
  const int quad = lane >> 4, l15 = lane & 15;

  f32x4 acc[4][4];
#pragma unroll
  for (int i = 0; i < 4; i++)
#pragma unroll
    for (int j = 0; j < 4; j++) acc[i][j] = (f32x4){0.f, 0.f, 0.f, 0.f};

  const ushort* AhB = Ah + (size_t)bm * K;
  const ushort* BhB = Wh + (size_t)bn * K;

  for (int k0 = 0; k0 < K; k0 += 64) {
#pragma unroll
    for (int i = 0; i < 4; i++) {
      int idx = i * 256 + t;
      int row = idx >> 3, c = idx & 7;
      int k8  = c ^ (row & 7);
      size_t off = (size_t)row * K + k0 + k8 * 8;
      ((uint4*)AhS)[idx] = *(const uint4*)(AhB + off);
      ((uint4*)BhS)[idx] = *(const uint4*)(BhB + off);
    }
    __syncthreads();
#pragma unroll
    for (int ks = 0; ks < 2; ks++) {
      f16x8 ah[4], bh[4];
#pragma unroll
      for (int i = 0; i < 4; i++) {
        int row = wm * 64 + i * 16 + l15;
        int k8  = ks * 4 + quad;
        int ci  = k8 ^ (row & 7);
        ah[i] = ((const f16x8*)AhS)[row * 8 + ci];
        int nrow = wn * 64 + i * 16 + l15;
        int cj   = k8 ^ (nrow & 7);
        bh[i] = ((const f16x8*)BhS)[nrow * 8 + cj];
      }
#pragma unroll
      for (int i = 0; i < 4; i++)
#pragma unroll
        for (int j = 0; j < 4; j++)
          acc[i][j] = __builtin_amdgcn_mfma_f32_16x16x32_f16(ah[i], bh[j], acc[i][j], 0, 0, 0);
    }
    __syncthreads();
  }

  float bv[4], scv[4], shv[4];
#pragma unroll
  for (int j = 0; j < 4; j++) {
    int col = bn + wn*64 + j*16 + l15;
    if (BIAS)    bv[j]  = bias[col];
    if (RESIDBN) { scv[j] = rsc[col]; shv[j] = rsh[col]; }
  }
  float sj[4] = {0.f,0.f,0.f,0.f}, qj[4] = {0.f,0.f,0.f,0.f};
#pragma unroll
  for (int i = 0; i < 4; i++) {
#pragma unroll
    for (int r = 0; r < 4; r++) {
      int row = bm + wm*64 + i*16 + quad*4 + r;
#pragma unroll
      for (int j = 0; j < 4; j++) {
        int col = bn + wn*64 + j*16 + l15;
        float v = acc[i][j][r];
        if (BIAS)    v += bv[j];
        if (RELU)    v = fmaxf(v, 0.f);
        if (RESIDBN) {
          float rr = h2f(rh[(size_t)row * Ntot + col]);
          v += fmaf(rr, scv[j], shv[j]);
        }
        if (OUTQKV) {
          if (bn == 0) {                     // Q (pre-scaled) -> head-major fp16
            o0[((size_t)(col >> 4) * ROWS + row) * 16 + (col & 15)] = f2h_bits(v);
          } else if (bn == 128) {            // K -> head-major fp16
            int c = col - 128;
            o1[((size_t)(c >> 4) * ROWS + row) * 16 + (c & 15)] = f2h_bits(v);
          } else {                           // V -> head-major single fp16
            int c = col - 256;
            o2[((size_t)(c >> 4) * ROWS + row) * 16 + (c & 15)] = f2h_bits(v);
          }
        }
        if (OUT16) o0[(size_t)row * Ntot + col] = f2h_bits(v);
        if (STATS) { sj[j] += v; qj[j] = fmaf(v, v, qj[j]); }
      }
    }
  }
  if (STATS) {
#pragma unroll
    for (int j = 0; j < 4; j++) {
      sj[j] += __shfl_xor(sj[j], 16); sj[j] += __shfl_xor(sj[j], 32);
      qj[j] += __shfl_xor(qj[j], 16); qj[j] += __shfl_xor(qj[j], 32);
    }
    float* ssum = (float*)AhS;     // safe: k-loop ended with barrier
    float* ssq  = ssum + 128;
    if (t < 128) { ssum[t] = 0.f; ssq[t] = 0.f; }
    __syncthreads();
    if (quad == 0) {
#pragma unroll
      for (int j = 0; j < 4; j++) {
        int col = wn*64 + j*16 + l15;
        atomicAdd(&ssum[col], sj[j]);
        atomicAdd(&ssq[col],  qj[j]);
      }
    }
    __syncthreads();
    if (t < 128) {
      atomicAdd(&psum[t], ssum[t]);
      atomicAdd(&psq[t],  ssq[t]);
    }
  }
}

// ---------------- fused FFN (64-row blocks, 2 blocks/CU): hid stays in LDS ----------------
// Block = 64 rows; 4 waves each compute a 64x32 output strip (acc[4][2]).
// 4 f-chunks of 128: stage W1c -> MFMA hid -> relu->fp16 -> HB -> stage W2c -> MFMA out-accum.
// Per-element accumulation order identical to separate FFN1/FFN2 kernels.
__global__ __launch_bounds__(256, 2) void ffn_fused(
    const ushort* __restrict__ h,        // [ROWS][128] fp16 (A; also residual source)
    const ushort* __restrict__ w1,       // [512][128] folded fp16
    const float* __restrict__ b1f,       // [512] folded bias
    const ushort* __restrict__ w2t,      // [128][512] fp16
    const float* __restrict__ b2,        // [128]
    const float* __restrict__ rsc, const float* __restrict__ rsh,
    ushort* hout,                        // aliases h (in-place row update)
    float* __restrict__ psum, float* __restrict__ psq)
{
  __shared__ ushort Ash[2*64*64];        // 16KB  A halves by k: [half][row64][64]
  __shared__ ushort WB [2*128*64];       // 32KB  W1 chunk, then W2 chunk: [half][row128][64]
  __shared__ ushort HB [2*64*72];        // 18KB  relu(hid): [fhalf][row64][72] (bank stagger)
  const int t    = threadIdx.x;
  const int bm   = blockIdx.x * 64;
  const int lane = t & 63;
  const int w    = t >> 6;               // wave 0..3 -> cols w*32..w*32+31
  const int quad = lane >> 4, l15 = lane & 15;

  // ---- stage A (64 rows x 128 k) ----
  {
    const ushort* AB = h + (size_t)bm * 128;
    for (int half = 0; half < 2; half++)
#pragma unroll
      for (int i = 0; i < 2; i++) {
        int idx = i * 256 + t;            // 512 uint4 per half
        int row = idx >> 3, c = idx & 7;
        int k8  = c ^ (row & 7);
        ((uint4*)(Ash + half*4096))[idx] = *(const uint4*)(AB + (size_t)row*128 + half*64 + k8*8);
      }
  }

  f32x4 aco[4][2];
#pragma unroll
  for (int i = 0; i < 4; i++)
#pragma unroll
    for (int j = 0; j < 2; j++) aco[i][j] = (f32x4){0.f, 0.f, 0.f, 0.f};

  __syncthreads();

  for (int ch = 0; ch < 4; ch++) {
    // ---- stage W1 chunk: f-rows ch*128..+127, k 0..127 ----
    {
      const ushort* W1B = w1 + (size_t)ch * 128 * 128;
      for (int half = 0; half < 2; half++)
#pragma unroll
        for (int i = 0; i < 4; i++) {
          int idx = i * 256 + t;
          int row = idx >> 3, c = idx & 7;
          int k8  = c ^ (row & 7);
          ((uint4*)(WB + half*8192))[idx] = *(const uint4*)(W1B + (size_t)row*128 + half*64 + k8*8);
        }
    }
    __syncthreads();
    // ---- hid chunk MFMA: [row64][f128], K=128 ----
    f32x4 ach[4][2];
#pragma unroll
    for (int i = 0; i < 4; i++)
#pragma unroll
      for (int j = 0; j < 2; j++) ach[i][j] = (f32x4){0.f, 0.f, 0.f, 0.f};
#pragma unroll
    for (int ks = 0; ks < 4; ks++) {
      int half = ks >> 1, k8 = (ks & 1)*4 + quad;
      f16x8 ah[4], bh[2];
#pragma unroll
      for (int i = 0; i < 4; i++) {
        int row = i*16 + l15;
        int ci  = k8 ^ (row & 7);
        ah[i] = ((const f16x8*)(Ash + half*4096))[row*8 + ci];
      }
#pragma unroll
      for (int j = 0; j < 2; j++) {
        int fr = w*32 + j*16 + l15;
        int cj = k8 ^ (fr & 7);
        bh[j] = ((const f16x8*)(WB + half*8192))[fr*8 + cj];
      }
#pragma unroll
      for (int i = 0; i < 4; i++)
#pragma unroll
        for (int j = 0; j < 2; j++)
          ach[i][j] = __builtin_amdgcn_mfma_f32_16x16x32_f16(ah[i], bh[j], ach[i][j], 0, 0, 0);
    }
    __syncthreads();       // all waves done reading WB (W1c)
    // ---- bias + relu -> HB (fp16, swizzled, pitch 72) ----
    {
      float bv1[2];
#pragma unroll
      for (int j = 0; j < 2; j++) bv1[j] = b1f[ch*128 + w*32 + j*16 + l15];
#pragma unroll
      for (int i = 0; i < 4; i++)
#pragma unroll
        for (int r = 0; r < 4; r++) {
          int row = i*16 + quad*4 + r;
#pragma unroll
          for (int j = 0; j < 2; j++) {
            float hv = fmaxf(ach[i][j][r] + bv1[j], 0.f);
            int f   = w*32 + j*16 + l15;
            int hf  = f >> 6, k6 = f & 63;
            int ci8 = (k6 >> 3) ^ (row & 7);
            HB[hf*4608 + row*72 + ci8*8 + (k6 & 7)] = f2h_bits(hv);
          }
        }
    }
    // ---- stage W2 chunk: d-rows 0..127, k = f-chunk (pitch 512) ----
    {
      const ushort* W2B = w2t + ch * 128;
      for (int half = 0; half < 2; half++)
#pragma unroll
        for (int i = 0; i < 4; i++) {
          int idx = i * 256 + t;
          int row = idx >> 3, c = idx & 7;
          int k8  = c ^ (row & 7);
          ((uint4*)(WB + half*8192))[idx] = *(const uint4*)(W2B + (size_t)row*512 + half*64 + k8*8);
        }
    }
    __syncthreads();       // HB + WB(W2c) ready
    // ---- out accumulate: [row64][d128], K=f 128 ----
#pragma unroll
    for (int ks = 0; ks < 4; ks++) {
      int half = ks >> 1, k8 = (ks & 1)*4 + quad;
      f16x8 ah[4], bh[2];
#pragma unroll
      for (int i = 0; i < 4; i++) {
        int row = i*16 + l15;
        int ci  = k8 ^ (row & 7);
        ah[i] = *(const f16x8*)&HB[half*4608 + row*72 + ci*8];
      }
#pragma unroll
      for (int j = 0; j < 2; j++) {
        int dr = w*32 + j*16 + l15;
        int cj = k8 ^ (dr & 7);
        bh[j] = ((const f16x8*)(WB + half*8192))[dr*8 + cj];
      }
#pragma unroll
      for (int i = 0; i < 4; i++)
#pragma unroll
        for (int j = 0; j < 2; j++)
          aco[i][j] = __builtin_amdgcn_mfma_f32_16x16x32_f16(ah[i], bh[j], aco[i][j], 0, 0, 0);
    }
    __syncthreads();       // done reading HB + WB; next chunk may overwrite
  }

  // ---- epilogue: + b2 + BN1-folded residual (residual read from Ash) -> h + BN2 stats ----
  float bv[2], scv[2], shv[2];
#pragma unroll
  for (int j = 0; j < 2; j++) {
    int col = w*32 + j*16 + l15;
    bv[j]  = b2[col];
    scv[j] = rsc[col]; shv[j] = rsh[col];
  }
  float sj[2] = {0.f,0.f}, qj[2] = {0.f,0.f};
#pragma unroll
  for (int i = 0; i < 4; i++) {
#pragma unroll
    for (int r = 0; r < 4; r++) {
      int rloc = i*16 + quad*4 + r;
      int row  = bm + rloc;
#pragma unroll
      for (int j = 0; j < 2; j++) {
        int col = w*32 + j*16 + l15;
        float v = aco[i][j][r] + bv[j];
        // residual = h[row][col] = A[rloc][k=col], resident in Ash
        int k6 = col & 63, half = col >> 6;
        int ci = (k6 >> 3) ^ (rloc & 7);
        float rr = h2f(Ash[half*4096 + rloc*64 + ci*8 + (k6 & 7)]);
        v += fmaf(rr, scv[j], shv[j]);
        hout[(size_t)row * 128 + col] = f2h_bits(v);
        sj[j] += v; qj[j] = fmaf(v, v, qj[j]);
      }
    }
  }
#pragma unroll
  for (int j = 0; j < 2; j++) {
    sj[j] += __shfl_xor(sj[j], 16); sj[j] += __shfl_xor(sj[j], 32);
    qj[j] += __shfl_xor(qj[j], 16); qj[j] += __shfl_xor(qj[j], 32);
  }
  __syncthreads();               // all residual reads from Ash complete
  float* ssum = (float*)Ash;
  float* ssq  = ssum + 128;
  if (t < 128) { ssum[t] = 0.f; ssq[t] = 0.f; }
  __syncthreads();
  if (quad == 0) {
#pragma unroll
    for (int j = 0; j < 2; j++) {
      int col = w*32 + j*16 + l15;
      atomicAdd(&ssum[col], sj[j]);
      atomicAdd(&ssq[col],  qj[j]);
    }
  }
  __syncthreads();
  if (t < 128) {
    atomicAdd(&psum[t], ssum[t]);
    atomicAdd(&psq[t],  ssq[t]);
  }
}

// ---------------- MFMA fused attention; block 0 zeroes BN2 accumulators ----------------
__global__ __launch_bounds__(256) void attn_kernel(const ushort* __restrict__ qs,
    const ushort* __restrict__ ks, const ushort* __restrict__ vh,
    ushort* __restrict__ hd, float* __restrict__ pb_s, float* __restrict__ pb_q)
{
  __shared__ __align__(16) _Float16 Ksh[208*24];    // [key][kd], pitch 24
  __shared__ __align__(16) _Float16 VTh[16*216];    // V^T [kd][key], pitch 216
  const int b  = blockIdx.x >> 3;
  const int hh = blockIdx.x & 7;
  const int t  = threadIdx.x;
  if (blockIdx.x == 0 && t < 128) { pb_s[t] = 0.f; pb_q[t] = 0.f; }  // zero BN2 accum
  const size_t rb = (size_t)b * N_;
  const size_t hb = ((size_t)hh * ROWS + rb) * 16;   // element base of this (head, batch)

  // ---- stage K [208][24]: 16B loads, zero pad rows 200..207 ----
  for (int i = t; i < 208*2; i += 256) {
    int n = i >> 1, half = i & 1;
    uint4 kv = {0u, 0u, 0u, 0u};
    if (n < N_) kv = *(const uint4*)(ks + hb + n*16 + half*8);
    *(uint4*)&Ksh[n*24 + half*8] = kv;
  }
  // ---- stage V^T: 16B loads + LDS transpose scatter ----
  for (int i = t; i < 208*2; i += 256) {
    int n = i >> 1, half = i & 1;
    uint4 v0 = {0u, 0u, 0u, 0u};
    if (n < N_) v0 = *(const uint4*)(vh + hb + n*16 + half*8);
    const ushort* e0 = (const ushort*)&v0;
#pragma unroll
    for (int q = 0; q < 8; q++)
      ((ushort*)VTh)[(half*8 + q)*216 + n] = e0[q];
  }
  __syncthreads();

  const int lane = t & 63;
  const int w    = t >> 6;
  const int l15  = lane & 15;
  const int g    = lane >> 4;

  for (int qt = w; qt < 13; qt += 4) {
    int qr  = qt*16 + l15;                 // query row in [0,208)
    int qrc = qr < N_ ? qr : N_-1;         // clamp pad rows (results discarded)
    f16x4 bq = *(const f16x4*)(qs + hb + (size_t)qrc*16 + g*4);

    // S^T tiles: ct[kt] holds scores (log2-units) for keys kt*16+g*4+r, query q=l15
    f32x4 ct[13];
#pragma unroll
    for (int kt = 0; kt < 13; kt++) {
      f16x4 ak = *(const f16x4*)&Ksh[(kt*16 + l15)*24 + g*4];
      ct[kt] = __builtin_amdgcn_mfma_f32_16x16x16f16(ak, bq, (f32x4){0.f,0.f,0.f,0.f}, 0, 0, 0);
    }
    // mask pad keys (192+g*4+r >= 200)
#pragma unroll
    for (int r = 0; r < 4; r++)
      if (g*4 + r >= 8) ct[12][r] = -1e30f;

    // row max over 13 tiles then across lane groups
    float m0 = -1e30f, m1 = -1e30f;
#pragma unroll
    for (int kt = 0; kt < 13; kt++) {
      m0 = fmaxf(m0, fmaxf(ct[kt][0], ct[kt][1]));
      m1 = fmaxf(m1, fmaxf(ct[kt][2], ct[kt][3]));
    }
    float m = fmaxf(m0, m1);
    m = fmaxf(m, __shfl_xor(m, 16));
    m = fmaxf(m, __shfl_xor(m, 32));

    // exp2 + row sum
    float la0 = 0.f, la1 = 0.f, la2 = 0.f, la3 = 0.f;
#pragma unroll
    for (int kt = 0; kt < 13; kt++) {
      float p0 = __builtin_amdgcn_exp2f(ct[kt][0] - m);
      float p1 = __builtin_amdgcn_exp2f(ct[kt][1] - m);
      float p2 = __builtin_amdgcn_exp2f(ct[kt][2] - m);
      float p3 = __builtin_amdgcn_exp2f(ct[kt][3] - m);
      la0 += p0; la1 += p1; la2 += p2; la3 += p3;
      ct[kt][0] = p0; ct[kt][1] = p1; ct[kt][2] = p2; ct[kt][3] = p3;
    }
    float l = (la0 + la1) + (la2 + la3);
    l += __shfl_xor(l, 16);
    l += __shfl_xor(l, 32);

    // O^T = V^T P^T — P^T B-frags come straight from ct
    f32x4 och = {0.f,0.f,0.f,0.f};
#pragma unroll
    for (int kt = 0; kt < 13; kt++) {
      f16x4 pt = { (_Float16)ct[kt][0], (_Float16)ct[kt][1],
                   (_Float16)ct[kt][2], (_Float16)ct[kt][3] };
      f16x4 avh = *(const f16x4*)&VTh[l15*216 + kt*16 + g*4];
      och = __builtin_amdgcn_mfma_f32_16x16x16f16(avh, pt, och, 0, 0, 0);
    }

    if (qr < N_) {
      float inv = __builtin_amdgcn_rcpf(l);
      ushort o16[4];
#pragma unroll
      for (int r = 0; r < 4; r++) o16[r] = f2h_bits(och[r] * inv);
      uint2 p;
      p.x = (uint)o16[0] | ((uint)o16[1] << 16);
      p.y = (uint)o16[2] | ((uint)o16[3] << 16);
      *(uint2*)(hd + (rb + qr)*128 + hh*16 + g*4) = p;
    }
  }
}

// ---------------- final: BN2-finalize + apply + per-batch mean ----------------
__global__ __launch_bounds__(256) void bn_mean_final(const ushort* __restrict__ h,
    const float* __restrict__ pb_s, const float* __restrict__ pb_q,
    const float* __restrict__ gamma, const float* __restrict__ beta,
    float* __restrict__ outh, float* __restrict__ mout)
{
  __shared__ float part[2][128];
  int b = blockIdx.x;
  int t = threadIdx.x;
  int d = t & 127, half = t >> 7;
  float sc, sh;
  bn_reduce(pb_s, pb_q, gamma, beta, d, sc, sh);
  float s = 0.f;
  for (int n = half*100; n < half*100 + 100; n++) {
    size_t idx = ((size_t)b * N_ + n) * 128 + d;
    float v = fmaf(h2f(h[idx]), sc, sh);
    outh[idx] = v;
    s += v;
  }
  part[half][d] = s;
  __syncthreads();
  if (half == 0) mout[b * 128 + d] = (part[0][d] + part[1][d]) * (1.f / N_);
}

extern "C" void kernel_launch(void* const* d_in, const int* in_sizes, int n_in,
                              void* d_out, int out_size, void* d_ws, size_t ws_size,
                              hipStream_t stream)
{
  const float* x    = (const float*)d_in[0];
  const float* Wemb = (const float*)d_in[1];
  const float* bemb = (const float*)d_in[2];
  const float* Wq   = (const float*)d_in[3];
  const float* Wk   = (const float*)d_in[4];
  const float* Wv   = (const float*)d_in[5];
  const float* Wo   = (const float*)d_in[6];
  const float* bn1g = (const float*)d_in[7];
  const float* bn1b = (const float*)d_in[8];
  const float* W1   = (const float*)d_in[9];
  const float* b1   = (const float*)d_in[10];
  const float* W2   = (const float*)d_in[11];
  const float* b2   = (const float*)d_in[12];
  const float* bn2g = (const float*)d_in[13];
  const float* bn2b = (const float*)d_in[14];
  float* out = (float*)d_out;

  char* wsb = (char*)d_ws;
  ushort* h     = (ushort*)wsb;                     // 13,107,200 B (fp16 residual stream)
  char*   phase = wsb + 13107200;                   // attn scratch
  ushort* qsb   = (ushort*)phase;                   // 13,107,200 B (Q head-major)
  ushort* ksb   = (ushort*)(phase + 13107200);      // 13,107,200 B (K head-major)
  ushort* vhh   = (ushort*)(phase + 26214400);      // 13,107,200 B (V fp16)
  ushort* hd    = (ushort*)(phase + 39321600);      // 13,107,200 B (heads fp16)
  char*   wp    = wsb + 65536000;
  ushort* woT   = (ushort*)wp;                      // 98,304 B
  ushort* w2T   = (ushort*)(wp + 98304);            // 393,216 B
  ushort* fqkvw = (ushort*)(wp + 491520);           // 98,304 B
  ushort* fw1w  = (ushort*)(wp + 589824);           // 131,072 B
  float*  fqkv_b = (float*)(wp + 720896);           // 1,536 B
  float*  fw1_b  = (float*)(wp + 722432);           // 2,048 B
  float*  pa_s   = (float*)(wp + 724480);           // 512 B (BN1 sum accum)
  float*  pa_q   = (float*)(wp + 724992);           // 512 B
  float*  pb_s   = (float*)(wp + 725504);           // 512 B (BN2 sum accum)
  float*  pb_q   = (float*)(wp + 726016);           // 512 B
  float*  sc_a   = (float*)(wp + 726528);
  float*  sh_a   = (float*)(wp + 727040);
  float*  sc_b   = (float*)(wp + 727552);
  float*  sh_b   = (float*)(wp + 728064);

  init_kernel<<<7361, 256, 0, stream>>>(x, Wemb, bemb, Wo, W2, h, woT, w2T,
                                        pa_s, pa_q, pb_s, pb_q);

  for (int l = 0; l < L_; l++) {
    // fold BN2(prev layer) into QKV weights; publishes sc_b/sh_b; zeroes BN1 accum
    fold_qkv<<<384, 128, 0, stream>>>(Wq + l*16384, Wk + l*16384, Wv + l*16384,
                                      pb_s, pb_q,
                                      l == 0 ? nullptr : bn2g + (l-1)*128,
                                      l == 0 ? nullptr : bn2b + (l-1)*128,
                                      fqkvw, fqkv_b, sc_b, sh_b, pa_s, pa_q);
    // QKV projection -> head-major Q/K/V fp16
    gemm_mfma<128, true, false, false, true, false, false>
        <<<dim3(3, 400), 256, 0, stream>>>(
        h, fqkvw, fqkv_b, nullptr, nullptr, nullptr,
        qsb, ksb, vhh, nullptr, nullptr, 384);
    // attention -> heads fp16 [row][128]; zeroes BN2 accumulators
    attn_kernel<<<B_ * H_, 256, 0, stream>>>(qsb, ksb, vhh, hd, pb_s, pb_q);
    // out-proj + BN-folded residual -> h fp16 + BN1 stats (atomic)
    gemm_mfma<128, false, false, true, false, true, true>
        <<<dim3(1, 400), 256, 0, stream>>>(
        hd, woT + l*16384, nullptr, h, sc_b, sh_b,
        h, nullptr, nullptr, pa_s, pa_q, 128);
    // fold BN1 into W1; publishes sc_a/sh_a
    fold_w1<<<512, 128, 0, stream>>>(W1 + l*65536, b1 + l*512,
                                     pa_s, pa_q, bn1g + l*128, bn1b + l*128,
                                     fw1w, fw1_b, sc_a, sh_a);
    // fused FFN1+ReLU+FFN2 + bias + BN1-folded residual -> h fp16 + BN2 stats (atomic)
    ffn_fused<<<800, 256, 0, stream>>>(
        h, fw1w, fw1_b, w2T + l*65536, b2 + l*128, sc_a, sh_a,
        h, pb_s, pb_q);
  }

  bn_mean_final<<<B_, 256, 0, stream>>>(h, pb_s, pb_q,
                                        bn2g + 2*128, bn2b + 2*128, out, out + BND);
}